// Round 17
// baseline (19.207 us; speedup 1.0000x reference)
//
#include <hip/hip_runtime.h>
#include <math.h>

#define NFACE 512
#define NVERT 642
#define NPIX  (256 * 256)
#define DXS   (2.0f / 256.0f)

// Camera constants (input-independent, folded from the reference):
#define EYEX 2.732f
#define EYEZ (-1.6728675276352845e-16f)
#define CC0  (6.123233995736766e-17f)

// Fused renderer, single graph node. 512 blocks x 256 threads (4 waves),
// block = 16x8 half-tile -> 2-4 independent blocks per CU (no shared
// barriers: block A's barrier/atomic stalls overlap block B's issue).
// Phase 1 (2 faces/thread): exact corner-bound classify (reject/full/
// partial) + half-tile depth prune (M = min over full faces of dmax+md;
// dmin-md > M can never win the argmin — removes only reference-losing
// faces). Append via wave ballot compaction: ONE LDS atomic per wave per
// list (vs ~300 serialized per-thread atomics).
// Phase 2: list split across 4 waves (k%4==w), each wave covers all 128 px
// (2 px/thread). Merge: [4][128] LDS u32-min.
// Pack (depth_bits & ~511) | face — order/partition-invariant, ties ->
// smaller face index (jnp.argmin first-index).
// Epilogue recomputes winner coefs from sverts (no sf0/sf1 -> LDS ~38KB).
// Finish: bsum[blockIdx] plain store, fence, atomicAdd(cntr,1); the block
// seeing old%512==511 (exactly one per 512 increments, any start value —
// 0xAA poison ok, no reset) fences, reads partials via atomicAdd(+0.0f)
// (device-scope coherent), reduces, plain-stores out[0] (idempotent).
// Records: w_k = A_k*Py+B_k*Px+C_k (== ref w_k/denom, sign folded),
// w2 = 1-w0-w1; depth = DA*Py+DB*Px+DC; inside => depth>0 (camera z>1.73).
__global__ __launch_bounds__(256) void render_loss(
    const float* __restrict__ verts,   // (642,3)
    const int*   __restrict__ faces,   // (512,3)
    const float* __restrict__ tex,     // (512,4,4,4,3)
    const float* __restrict__ ref,     // (3,256,256)
    float* __restrict__ bsum,          // (512) per-block partials (d_ws)
    unsigned* __restrict__ cntr,       // completion counter (d_ws)
    float* __restrict__ out)           // scalar
{
    __shared__ float  sverts[NVERT * 3];
    __shared__ float4 flist[NFACE];      // full: DA,DB,DC,fid
    __shared__ float4 pl0[NFACE];        // partial: A0,B0,C0,A1
    __shared__ float4 pl1[NFACE];        // partial: B1,C1,DA,DB
    __shared__ float2 pld[NFACE];        // partial: DC,fid
    __shared__ unsigned marr[4][128];    // per-wave per-pixel packs
    __shared__ int   fcnt, pcnt;
    __shared__ unsigned Mu;
    __shared__ float wsum[4];
    __shared__ int sfinish;

    int tid  = threadIdx.x;
    int lane = tid & 63;
    int w    = tid >> 6;
    if (tid == 0) { fcnt = 0; pcnt = 0; Mu = 0x7f800000u; sfinish = 0; }

    for (int k = tid; k < NVERT * 3; k += 256) sverts[k] = verts[k];
    __syncthreads();

    int tileX = (blockIdx.x & 15) << 4;      // 16 tiles across
    int tileY = (blockIdx.x >> 4) << 3;      // 32 tiles down, 8 rows each
    float xlo = (tileX + 0.5f)  * DXS - 1.0f;
    float xhi = (tileX + 15.5f) * DXS - 1.0f;
    float yhi = 1.0f - (tileY + 0.5f) * DXS;
    float ylo = 1.0f - (tileY + 7.5f) * DXS;

    // ---- phase 1a: setup + classify (2 faces/thread, results in regs) ----
    float rc[2][9];      // A0,B0,C0,A1,B1,C1,DA,DB,DC
    int   rcls[2];       // 0=rejected, 1=full, 2=partial
    float rdmn[2];       // dmin - margin
#pragma unroll
    for (int it = 0; it < 2; ++it) {
        int f = tid + it * 256;
        rcls[it] = 0;
        float vx[3], vy[3], vz[3];
#pragma unroll
        for (int k = 0; k < 3; ++k) {
            int vi = faces[f * 3 + k];
            float px = sverts[vi * 3 + 0];
            float py = sverts[vi * 3 + 1];
            float pz = sverts[vi * 3 + 2];
            float dx = px - EYEX;
            float dz = pz - EYEZ;
            vx[k] = CC0 * dx + dz;
            vy[k] = py;
            vz[k] = -dx + CC0 * dz;
        }
        float ax = vx[0], ay = vy[0];
        float bx = vx[1], by = vy[1];
        float cx = vx[2], cy = vy[2];
        float denom = (bx - ax) * (cy - ay) - (by - ay) * (cx - ax);
        if (fabsf(denom) <= 1e-8f) continue;      // degenerate

        float si = 1.0f / denom;                  // sign folded
        float e0x = cx - bx, e0y = cy - by;
        float e1x = ax - cx, e1y = ay - cy;
        float A0 = e0x * si, B0 = -e0y * si, C0 = (e0y * bx - e0x * by) * si;
        float A1 = e1x * si, B1 = -e1y * si, C1 = (e1y * cx - e1x * cy) * si;
        float A2 = -(A0 + A1), B2 = -(B0 + B1), C2 = 1.0f - C0 - C1;
        float DA = A0 * vz[0] + A1 * vz[1] + A2 * vz[2];
        float DB = B0 * vz[0] + B1 * vz[1] + B2 * vz[2];
        float DC = C0 * vz[0] + C1 * vz[1] + C2 * vz[2];

        float bxmn = fminf(fminf(ax, bx), cx), bxmx = fmaxf(fmaxf(ax, bx), cx);
        float bymn = fminf(fminf(ay, by), cy), bymx = fmaxf(fmaxf(ay, by), cy);
        if ((bxmn > xhi + 1e-5f) | (bxmx < xlo - 1e-5f) |
            (bymn > yhi + 1e-5f) | (bymx < ylo - 1e-5f)) continue;

        float wmx[3], wmn[3], mg[3];
        float As[3] = {A0, A1, A2}, Bs[3] = {B0, B1, B2}, Cs[3] = {C0, C1, C2};
#pragma unroll
        for (int k = 0; k < 3; ++k) {
            float t1 = As[k] * ylo, t2 = As[k] * yhi;
            float u1 = Bs[k] * xlo, u2 = Bs[k] * xhi;
            wmx[k] = fmaxf(t1, t2) + fmaxf(u1, u2) + Cs[k];
            wmn[k] = fminf(t1, t2) + fminf(u1, u2) + Cs[k];
            mg[k]  = (fabsf(As[k]) + fabsf(Bs[k]) + fabsf(Cs[k])) * 2e-6f;
        }
        if ((wmx[0] < -mg[0]) | (wmx[1] < -mg[1]) | (wmx[2] < -mg[2])) continue;
        bool full = (wmn[0] > mg[0]) & (wmn[1] > mg[1]) & (wmn[2] > mg[2]);

        float t1 = DA * ylo, t2 = DA * yhi;
        float u1 = DB * xlo, u2 = DB * xhi;
        float dmx = fmaxf(t1, t2) + fmaxf(u1, u2) + DC;
        float dmn = fminf(t1, t2) + fminf(u1, u2) + DC;
        float md  = (fabsf(DA) + fabsf(DB) + fabsf(DC)) * 2e-6f + 1e-4f;
        rdmn[it] = dmn - md;
        rcls[it] = full ? 1 : 2;
        rc[it][0] = A0; rc[it][1] = B0; rc[it][2] = C0;
        rc[it][3] = A1; rc[it][4] = B1; rc[it][5] = C1;
        rc[it][6] = DA; rc[it][7] = DB; rc[it][8] = DC;
        if (full) atomicMin(&Mu, __float_as_uint(dmx + md));
    }
    __syncthreads();

    // ---- phase 1b: depth-pruned append, ballot-compacted ----
    float M = __uint_as_float(Mu);
    unsigned long long ltm = (1ull << lane) - 1ull;
#pragma unroll
    for (int it = 0; it < 2; ++it) {
        bool alive = (rcls[it] != 0) && (rdmn[it] <= M);
        bool isf = alive && (rcls[it] == 1);
        bool isp = alive && (rcls[it] == 2);
        unsigned long long bf = __ballot(isf);
        unsigned long long bp = __ballot(isp);
        int fbase = 0, pbase = 0;
        if (lane == 0) {
            if (bf) fbase = atomicAdd(&fcnt, (int)__popcll(bf));
            if (bp) pbase = atomicAdd(&pcnt, (int)__popcll(bp));
        }
        fbase = __shfl(fbase, 0, 64);
        pbase = __shfl(pbase, 0, 64);
        float fb = __uint_as_float((unsigned)(tid + it * 256));
        if (isf) {
            int s = fbase + (int)__popcll(bf & ltm);
            flist[s] = make_float4(rc[it][6], rc[it][7], rc[it][8], fb);
        }
        if (isp) {
            int s = pbase + (int)__popcll(bp & ltm);
            pl0[s] = make_float4(rc[it][0], rc[it][1], rc[it][2], rc[it][3]);
            pl1[s] = make_float4(rc[it][4], rc[it][5], rc[it][6], rc[it][7]);
            pld[s] = make_float2(rc[it][8], fb);
        }
    }
    __syncthreads();
    int fc = fcnt, pc = pcnt;

    // ---- phase 2: wave w takes entries k%4==w, covers ALL 128 px ----
    int col   = lane & 15;
    int rbase = (lane >> 4) << 1;                 // rows rbase, rbase+1
    float Px  = (tileX + col + 0.5f) * DXS - 1.0f;
    float Py0 = 1.0f - (tileY + rbase + 0.5f) * DXS;

    unsigned pk0 = 0xFFFFFFFFu, pk1 = 0xFFFFFFFFu;

    for (int k = w; k < fc; k += 4) {
        float4 r = flist[k];
        float td = fmaf(r.y, Px, r.z);            // DB*Px + DC
        float d0 = fmaf(r.x, Py0, td);
        float d1 = fmaf(r.x, Py0 - DXS, td);
        unsigned fb = __float_as_uint(r.w);
        unsigned c0 = (__float_as_uint(d0) & 0xFFFFFE00u) | fb;
        unsigned c1 = (__float_as_uint(d1) & 0xFFFFFE00u) | fb;
        pk0 = pk0 < c0 ? pk0 : c0;
        pk1 = pk1 < c1 ? pk1 : c1;
    }

    for (int k = w; k < pc; k += 4) {
        float4 q0 = pl0[k];
        float4 q1 = pl1[k];
        float2 qd = pld[k];
        float t0 = fmaf(q0.y, Px, q0.z);          // B0*Px + C0
        float t1 = fmaf(q1.x, Px, q1.y);          // B1*Px + C1
        float td = fmaf(q1.w, Px, qd.x);          // DB*Px + DC
        unsigned fb = __float_as_uint(qd.y);
#pragma unroll
        for (int q = 0; q < 2; ++q) {
            float Py = Py0 - (float)q * DXS;
            float w0 = fmaf(q0.x, Py, t0);
            float w1 = fmaf(q0.w, Py, t1);
            float w2 = 1.0f - w0 - w1;
            float dp = fmaf(q1.z, Py, td);
            float mn = fminf(fminf(w0, w1), w2);
            unsigned cd = (__float_as_uint(dp) & 0xFFFFFE00u) | fb;
            cd = (mn >= 0.f) ? cd : 0xFFFFFFFFu;
            if (q == 0) pk0 = pk0 < cd ? pk0 : cd;
            if (q == 1) pk1 = pk1 < cd ? pk1 : cd;
        }
    }

    // ---- merge across 4 waves ----
    marr[w][(rbase + 0) * 16 + col] = pk0;
    marr[w][(rbase + 1) * 16 + col] = pk1;
    __syncthreads();

    // ---- phase 3: threads 0..127 finish pixel tid ----
    float loss = 0.f;
    if (tid < 128) {
        unsigned best = marr[0][tid];
#pragma unroll
        for (int ww = 1; ww < 4; ++ww) {
            unsigned m = marr[ww][tid];
            best = best < m ? best : m;
        }
        int i = tileX + (tid & 15);
        int j = tileY + (tid >> 4);
        float Pxe = (i + 0.5f) * DXS - 1.0f;
        float Pye = 1.0f - (j + 0.5f) * DXS;
        int p = j * 256 + i;
        float col0 = 0.f, col1 = 0.f, col2 = 0.f;
        if (best != 0xFFFFFFFFu) {
            int bf = (int)(best & 511u);
            float vx[3], vy[3];
#pragma unroll
            for (int kk = 0; kk < 3; ++kk) {
                int vi = faces[bf * 3 + kk];
                float px = sverts[vi * 3 + 0];
                float py = sverts[vi * 3 + 1];
                float pz = sverts[vi * 3 + 2];
                float dx = px - EYEX;
                float dz = pz - EYEZ;
                vx[kk] = CC0 * dx + dz;
                vy[kk] = py;
            }
            float ax = vx[0], ay = vy[0];
            float bx = vx[1], by = vy[1];
            float cx = vx[2], cy = vy[2];
            float denom = (bx - ax) * (cy - ay) - (by - ay) * (cx - ax);
            float si = 1.0f / denom;
            float e0x = cx - bx, e0y = cy - by;
            float e1x = ax - cx, e1y = ay - cy;
            float A0 = e0x * si, B0 = -e0y * si, C0 = (e0y * bx - e0x * by) * si;
            float A1 = e1x * si, B1 = -e1y * si, C1 = (e1y * cx - e1x * cy) * si;
            float w0 = fmaf(A0, Pye, fmaf(B0, Pxe, C0));
            float w1 = fmaf(A1, Pye, fmaf(B1, Pxe, C1));
            float w2 = 1.0f - w0 - w1;
            int t0 = (int)rintf(w0 * 3.0f); t0 = t0 < 0 ? 0 : (t0 > 3 ? 3 : t0);
            int t1 = (int)rintf(w1 * 3.0f); t1 = t1 < 0 ? 0 : (t1 > 3 ? 3 : t1);
            int t2 = (int)rintf(w2 * 3.0f); t2 = t2 < 0 ? 0 : (t2 > 3 ? 3 : t2);
            const float* tp = tex + ((((bf * 4 + t0) * 4 + t1) * 4 + t2) * 3);
            col0 = tanhf(tp[0]);
            col1 = tanhf(tp[1]);
            col2 = tanhf(tp[2]);
        }
        float r0 = ref[0 * NPIX + p];
        float r1 = ref[1 * NPIX + p];
        float r2 = ref[2 * NPIX + p];
        float e0 = col0 - r0, e1 = col1 - r1, e2 = col2 - r2;
        loss = e0 * e0 + e1 * e1 + e2 * e2;
    }

    // ---- block reduce (4 waves) ----
    for (int off = 32; off > 0; off >>= 1)
        loss += __shfl_down(loss, off, 64);
    if (lane == 0) wsum[w] = loss;
    __syncthreads();

    // ---- store partial, count completion, elected finisher reduces ----
    if (tid == 0) {
        bsum[blockIdx.x] = wsum[0] + wsum[1] + wsum[2] + wsum[3];
        __threadfence();
        unsigned old = atomicAdd(cntr, 1u);
        if ((old & 511u) == 511u) sfinish = 1;
    }
    __syncthreads();
    if (sfinish) {
        __threadfence();
        float v = atomicAdd(&bsum[tid], 0.0f) + atomicAdd(&bsum[tid + 256], 0.0f);
        for (int off = 32; off > 0; off >>= 1)
            v += __shfl_down(v, off, 64);
        if (lane == 0) wsum[w] = v;
        __syncthreads();
        if (tid == 0)
            out[0] = wsum[0] + wsum[1] + wsum[2] + wsum[3];
    }
}

extern "C" void kernel_launch(void* const* d_in, const int* in_sizes, int n_in,
                              void* d_out, int out_size, void* d_ws, size_t ws_size,
                              hipStream_t stream) {
    const float* verts = (const float*)d_in[0];
    const float* tex   = (const float*)d_in[1];
    const float* ref   = (const float*)d_in[2];
    const int*   faces = (const int*)d_in[3];
    float* out  = (float*)d_out;
    float* bsum = (float*)d_ws;                    // 512 floats
    unsigned* cntr = (unsigned*)((float*)d_ws + 512);

    render_loss<<<512, 256, 0, stream>>>(verts, faces, tex, ref, bsum, cntr, out);
}

// Round 18
// 15.666 us; speedup vs baseline: 1.2261x; 1.2261x over previous
//
#include <hip/hip_runtime.h>
#include <math.h>

#define NFACE 512
#define NVERT 642
#define NPIX  (256 * 256)
#define DXS   (2.0f / 256.0f)

// Camera constants (input-independent, folded from the reference):
#define EYEX 2.732f
#define EYEZ (-1.6728675276352845e-16f)
#define CC0  (6.123233995736766e-17f)

// R16 structure (best: 16.0us), plus latency-chain trims:
//  - ref pixel values prefetched at kernel START (HBM latency hides under
//    classify+raster instead of sitting at the end of the critical path)
//  - face indices prefetched before the vertex-staging barrier
// Single graph node. 256 blocks x 512 threads (2 waves/SIMD), block = 16x16
// tile. Phase 1 (1 face/thread): exact corner-bound classify + tile-level
// depth prune (M = min over full faces of dmax+md; dmin-md > M can never
// win the argmin — removes only reference-losing faces). Phase 2: list
// split across 8 waves (k%8==w), each wave covers ALL 256 px (4 px/thread).
// Merge: [8][256] LDS u32-min. Pack (depth_bits & ~511) | face — order/
// partition-invariant, ties -> smaller face index (jnp.argmin first-index).
// Finish: bsum[blockIdx] plain store, fence, atomicAdd(cntr,1); block seeing
// old%256==255 (exactly one per 256 increments, any start value — 0xAA
// poison ok, no reset) fences, reads partials via atomicAdd(+0.0f)
// (device-scope coherent), reduces, plain-stores out[0] (idempotent).
// Records: w_k = A_k*Py+B_k*Px+C_k (== ref w_k/denom, sign folded),
// w2 = 1-w0-w1; depth = DA*Py+DB*Px+DC; inside => depth>0 (camera z>1.73).
__global__ __launch_bounds__(512) void render_loss(
    const float* __restrict__ verts,   // (642,3)
    const int*   __restrict__ faces,   // (512,3)
    const float* __restrict__ tex,     // (512,4,4,4,3)
    const float* __restrict__ ref,     // (3,256,256)
    float* __restrict__ bsum,          // (256) per-block partials (d_ws)
    unsigned* __restrict__ cntr,       // completion counter (d_ws)
    float* __restrict__ out)           // scalar
{
    __shared__ float  sverts[NVERT * 3];
    __shared__ float4 sf0[NFACE];        // A0,B0,C0,A1   (epilogue)
    __shared__ float4 sf1[NFACE];        // B1,C1,DA,DB   (epilogue)
    __shared__ float4 flist[NFACE];      // full: DA,DB,DC,fid
    __shared__ float4 pl0[NFACE];        // partial: A0,B0,C0,A1
    __shared__ float4 pl1[NFACE];        // partial: B1,C1,DA,DB
    __shared__ float2 pld[NFACE];        // partial: DC,fid
    __shared__ unsigned marr[8][256];    // per-wave per-pixel packs
    __shared__ int   fcnt, pcnt;
    __shared__ unsigned Mu;
    __shared__ float wsum[8];
    __shared__ int sfinish;

    int tid = threadIdx.x;
    if (tid == 0) { fcnt = 0; pcnt = 0; Mu = 0x7f800000u; sfinish = 0; }

    int tileX = (blockIdx.x & 15) << 4;
    int tileY = (blockIdx.x >> 4) << 4;

    // ---- EARLY: prefetch my pixel's ref values (used only in epilogue) ----
    float rf0 = 0.f, rf1 = 0.f, rf2 = 0.f;
    if (tid < 256) {
        int p = (tileY + (tid >> 4)) * 256 + tileX + (tid & 15);
        rf0 = ref[0 * NPIX + p];
        rf1 = ref[1 * NPIX + p];
        rf2 = ref[2 * NPIX + p];
    }
    // ---- EARLY: prefetch my face's vertex indices (independent of LDS) ----
    int fvi0 = faces[tid * 3 + 0];
    int fvi1 = faces[tid * 3 + 1];
    int fvi2 = faces[tid * 3 + 2];

    for (int k = tid; k < NVERT * 3; k += 512) sverts[k] = verts[k];
    __syncthreads();

    float xlo = (tileX + 0.5f)  * DXS - 1.0f;
    float xhi = (tileX + 15.5f) * DXS - 1.0f;
    float yhi = 1.0f - (tileY + 0.5f)  * DXS;
    float ylo = 1.0f - (tileY + 15.5f) * DXS;

    // ---- phase 1a: setup + classify (1 face/thread, results in regs) ----
    float rc[9];         // A0,B0,C0,A1,B1,C1,DA,DB,DC
    int   rcls = 0;      // 0=rejected, 1=full, 2=partial
    float rdmn = 0.f;    // dmin - margin
    {
        int f = tid;
        int vi[3] = {fvi0, fvi1, fvi2};
        float vx[3], vy[3], vz[3];
#pragma unroll
        for (int k = 0; k < 3; ++k) {
            float px = sverts[vi[k] * 3 + 0];
            float py = sverts[vi[k] * 3 + 1];
            float pz = sverts[vi[k] * 3 + 2];
            float dx = px - EYEX;
            float dz = pz - EYEZ;
            vx[k] = CC0 * dx + dz;
            vy[k] = py;
            vz[k] = -dx + CC0 * dz;
        }
        float ax = vx[0], ay = vy[0];
        float bx = vx[1], by = vy[1];
        float cx = vx[2], cy = vy[2];
        float denom = (bx - ax) * (cy - ay) - (by - ay) * (cx - ax);
        if (fabsf(denom) > 1e-8f) {
            float si = 1.0f / denom;              // sign folded
            float e0x = cx - bx, e0y = cy - by;
            float e1x = ax - cx, e1y = ay - cy;
            float A0 = e0x * si, B0 = -e0y * si, C0 = (e0y * bx - e0x * by) * si;
            float A1 = e1x * si, B1 = -e1y * si, C1 = (e1y * cx - e1x * cy) * si;
            float A2 = -(A0 + A1), B2 = -(B0 + B1), C2 = 1.0f - C0 - C1;
            float DA = A0 * vz[0] + A1 * vz[1] + A2 * vz[2];
            float DB = B0 * vz[0] + B1 * vz[1] + B2 * vz[2];
            float DC = C0 * vz[0] + C1 * vz[1] + C2 * vz[2];

            sf0[f] = make_float4(A0, B0, C0, A1);
            sf1[f] = make_float4(B1, C1, DA, DB);

            float bxmn = fminf(fminf(ax, bx), cx), bxmx = fmaxf(fmaxf(ax, bx), cx);
            float bymn = fminf(fminf(ay, by), cy), bymx = fmaxf(fmaxf(ay, by), cy);
            bool bboxout = (bxmn > xhi + 1e-5f) | (bxmx < xlo - 1e-5f) |
                           (bymn > yhi + 1e-5f) | (bymx < ylo - 1e-5f);
            if (!bboxout) {
                float wmx[3], wmn[3], mg[3];
                float As[3] = {A0, A1, A2}, Bs[3] = {B0, B1, B2}, Cs[3] = {C0, C1, C2};
#pragma unroll
                for (int k = 0; k < 3; ++k) {
                    float t1 = As[k] * ylo, t2 = As[k] * yhi;
                    float u1 = Bs[k] * xlo, u2 = Bs[k] * xhi;
                    wmx[k] = fmaxf(t1, t2) + fmaxf(u1, u2) + Cs[k];
                    wmn[k] = fminf(t1, t2) + fminf(u1, u2) + Cs[k];
                    mg[k]  = (fabsf(As[k]) + fabsf(Bs[k]) + fabsf(Cs[k])) * 2e-6f;
                }
                bool rej = (wmx[0] < -mg[0]) | (wmx[1] < -mg[1]) | (wmx[2] < -mg[2]);
                if (!rej) {
                    bool full = (wmn[0] > mg[0]) & (wmn[1] > mg[1]) & (wmn[2] > mg[2]);
                    float t1 = DA * ylo, t2 = DA * yhi;
                    float u1 = DB * xlo, u2 = DB * xhi;
                    float dmx = fmaxf(t1, t2) + fmaxf(u1, u2) + DC;
                    float dmn = fminf(t1, t2) + fminf(u1, u2) + DC;
                    float md  = (fabsf(DA) + fabsf(DB) + fabsf(DC)) * 2e-6f + 1e-4f;
                    rdmn = dmn - md;
                    rcls = full ? 1 : 2;
                    rc[0] = A0; rc[1] = B0; rc[2] = C0;
                    rc[3] = A1; rc[4] = B1; rc[5] = C1;
                    rc[6] = DA; rc[7] = DB; rc[8] = DC;
                    if (full) atomicMin(&Mu, __float_as_uint(dmx + md));
                }
            }
        }
    }
    __syncthreads();

    // ---- phase 1b: depth-pruned dense append ----
    float M = __uint_as_float(Mu);
    if (rcls != 0 && rdmn <= M) {
        float fb = __uint_as_float((unsigned)tid);
        if (rcls == 1) {
            int s = atomicAdd(&fcnt, 1);
            flist[s] = make_float4(rc[6], rc[7], rc[8], fb);
        } else {
            int s = atomicAdd(&pcnt, 1);
            pl0[s] = make_float4(rc[0], rc[1], rc[2], rc[3]);
            pl1[s] = make_float4(rc[4], rc[5], rc[6], rc[7]);
            pld[s] = make_float2(rc[8], fb);
        }
    }
    __syncthreads();
    int fc = fcnt, pc = pcnt;

    // ---- phase 2: wave w takes list entries k%8==w, covers ALL 256 px ----
    int lane = tid & 63;
    int w    = tid >> 6;
    int col   = lane & 15;
    int rbase = (lane >> 4) << 2;                 // rows rbase..rbase+3
    float Px  = (tileX + col + 0.5f) * DXS - 1.0f;
    float Py0 = 1.0f - (tileY + rbase + 0.5f) * DXS;

    unsigned pk0 = 0xFFFFFFFFu, pk1 = 0xFFFFFFFFu;
    unsigned pk2 = 0xFFFFFFFFu, pk3 = 0xFFFFFFFFu;

    for (int k = w; k < fc; k += 8) {
        float4 r = flist[k];
        float td = fmaf(r.y, Px, r.z);            // DB*Px + DC
        float d0 = fmaf(r.x, Py0, td);
        float d1 = fmaf(r.x, Py0 - DXS, td);
        float d2 = fmaf(r.x, Py0 - 2.0f * DXS, td);
        float d3 = fmaf(r.x, Py0 - 3.0f * DXS, td);
        unsigned fb = __float_as_uint(r.w);
        unsigned c0 = (__float_as_uint(d0) & 0xFFFFFE00u) | fb;
        unsigned c1 = (__float_as_uint(d1) & 0xFFFFFE00u) | fb;
        unsigned c2 = (__float_as_uint(d2) & 0xFFFFFE00u) | fb;
        unsigned c3 = (__float_as_uint(d3) & 0xFFFFFE00u) | fb;
        pk0 = pk0 < c0 ? pk0 : c0;
        pk1 = pk1 < c1 ? pk1 : c1;
        pk2 = pk2 < c2 ? pk2 : c2;
        pk3 = pk3 < c3 ? pk3 : c3;
    }

    for (int k = w; k < pc; k += 8) {
        float4 q0 = pl0[k];
        float4 q1 = pl1[k];
        float2 qd = pld[k];
        float t0 = fmaf(q0.y, Px, q0.z);          // B0*Px + C0
        float t1 = fmaf(q1.x, Px, q1.y);          // B1*Px + C1
        float td = fmaf(q1.w, Px, qd.x);          // DB*Px + DC
        unsigned fb = __float_as_uint(qd.y);
#pragma unroll
        for (int q = 0; q < 4; ++q) {
            float Py = Py0 - (float)q * DXS;
            float w0 = fmaf(q0.x, Py, t0);
            float w1 = fmaf(q0.w, Py, t1);
            float w2 = 1.0f - w0 - w1;
            float dp = fmaf(q1.z, Py, td);
            float mn = fminf(fminf(w0, w1), w2);
            unsigned cd = (__float_as_uint(dp) & 0xFFFFFE00u) | fb;
            cd = (mn >= 0.f) ? cd : 0xFFFFFFFFu;
            if (q == 0) pk0 = pk0 < cd ? pk0 : cd;
            if (q == 1) pk1 = pk1 < cd ? pk1 : cd;
            if (q == 2) pk2 = pk2 < cd ? pk2 : cd;
            if (q == 3) pk3 = pk3 < cd ? pk3 : cd;
        }
    }

    // ---- merge across 8 waves ----
    marr[w][(rbase + 0) * 16 + col] = pk0;
    marr[w][(rbase + 1) * 16 + col] = pk1;
    marr[w][(rbase + 2) * 16 + col] = pk2;
    marr[w][(rbase + 3) * 16 + col] = pk3;
    __syncthreads();

    // ---- phase 3: threads 0..255 finish pixel tid ----
    float loss = 0.f;
    if (tid < 256) {
        unsigned best = marr[0][tid];
#pragma unroll
        for (int ww = 1; ww < 8; ++ww) {
            unsigned m = marr[ww][tid];
            best = best < m ? best : m;
        }
        int i = tileX + (tid & 15);
        int j = tileY + (tid >> 4);
        float Pxe = (i + 0.5f) * DXS - 1.0f;
        float Pye = 1.0f - (j + 0.5f) * DXS;
        float col0 = 0.f, col1 = 0.f, col2 = 0.f;
        if (best != 0xFFFFFFFFu) {
            int bf = (int)(best & 511u);
            float4 q0 = sf0[bf];
            float4 q1 = sf1[bf];
            float w0 = fmaf(q0.x, Pye, fmaf(q0.y, Pxe, q0.z));
            float w1 = fmaf(q0.w, Pye, fmaf(q1.x, Pxe, q1.y));
            float w2 = 1.0f - w0 - w1;
            int t0 = (int)rintf(w0 * 3.0f); t0 = t0 < 0 ? 0 : (t0 > 3 ? 3 : t0);
            int t1 = (int)rintf(w1 * 3.0f); t1 = t1 < 0 ? 0 : (t1 > 3 ? 3 : t1);
            int t2 = (int)rintf(w2 * 3.0f); t2 = t2 < 0 ? 0 : (t2 > 3 ? 3 : t2);
            const float* tp = tex + ((((bf * 4 + t0) * 4 + t1) * 4 + t2) * 3);
            col0 = tanhf(tp[0]);
            col1 = tanhf(tp[1]);
            col2 = tanhf(tp[2]);
        }
        float e0 = col0 - rf0, e1 = col1 - rf1, e2 = col2 - rf2;
        loss = e0 * e0 + e1 * e1 + e2 * e2;
    }

    // ---- block reduce (8 waves) ----
    for (int off = 32; off > 0; off >>= 1)
        loss += __shfl_down(loss, off, 64);
    if (lane == 0) wsum[w] = loss;
    __syncthreads();

    // ---- store partial, count completion, elected finisher reduces ----
    if (tid == 0) {
        bsum[blockIdx.x] = wsum[0] + wsum[1] + wsum[2] + wsum[3]
                         + wsum[4] + wsum[5] + wsum[6] + wsum[7];
        __threadfence();
        unsigned old = atomicAdd(cntr, 1u);
        if ((old & 255u) == 255u) sfinish = 1;
    }
    __syncthreads();
    if (sfinish) {
        __threadfence();
        float v = (tid < 256) ? atomicAdd(&bsum[tid], 0.0f) : 0.0f;
        for (int off = 32; off > 0; off >>= 1)
            v += __shfl_down(v, off, 64);
        if (lane == 0) wsum[w] = v;
        __syncthreads();
        if (tid == 0)
            out[0] = wsum[0] + wsum[1] + wsum[2] + wsum[3]
                   + wsum[4] + wsum[5] + wsum[6] + wsum[7];
    }
}

extern "C" void kernel_launch(void* const* d_in, const int* in_sizes, int n_in,
                              void* d_out, int out_size, void* d_ws, size_t ws_size,
                              hipStream_t stream) {
    const float* verts = (const float*)d_in[0];
    const float* tex   = (const float*)d_in[1];
    const float* ref   = (const float*)d_in[2];
    const int*   faces = (const int*)d_in[3];
    float* out  = (float*)d_out;
    float* bsum = (float*)d_ws;                    // 256 floats
    unsigned* cntr = (unsigned*)((float*)d_ws + 256);

    render_loss<<<256, 512, 0, stream>>>(verts, faces, tex, ref, bsum, cntr, out);
}